// Round 1
// baseline (153.870 us; speedup 1.0000x reference)
//
#include <hip/hip_runtime.h>
#include <math.h>

// DotDetectionLoss on MI355X.
// pred: (16, 4096, 4) f32 = [cls, x, y, conf]  -> float4 loads
// gt:   (16, 1024, 3) f32 = [cls, x, y]
// out:  float[2] = {obj_loss, reg_loss}
//
// Math: scores = sigmoid(2.5 - d) monotone in d => argmax(score) == argmin(d^2),
// valid radius (score >= 0.5) <=> d^2 <= 6.25. correct[p] via atomicOr scatter of
// per-target argmin winners; reg term only needed for correct preds (compacted list).

#define NB 16
#define NP 4096
#define NT 1024

// ws layout (4-byte words):
//   [0 .. NB*NP)        correct flags (unsigned)
//   [NB*NP]             list counter (unsigned)
//   [NB*NP+1]           bce sum (float)
//   [NB*NP+2]           score sum (float)
//   [NB*NP+3 .. +NB*NT) compacted list of correct global pred indices
// total ~328 KB

__global__ __launch_bounds__(256) void k_zero(unsigned* __restrict__ ws, int n) {
    int i = blockIdx.x * 256 + threadIdx.x;
    if (i < n) ws[i] = 0u;
}

// One block = 16 targets of one image; 4 waves x 4 targets each.
// Lanes stride over P; pred[b] staged through LDS in 1024-row chunks (16 KB).
__global__ __launch_bounds__(256) void k_match(const float4* __restrict__ pred,
                                               const float* __restrict__ gt,
                                               unsigned* __restrict__ flags,
                                               unsigned* __restrict__ counter,
                                               unsigned* __restrict__ list) {
    const int CP = 1024;                 // p chunk rows in LDS
    int b    = blockIdx.x >> 6;          // 64 blocks per image (1024 t / 16)
    int tblk = blockIdx.x & 63;
    int wave = threadIdx.x >> 6;
    int lane = threadIdx.x & 63;
    __shared__ float4 sp[CP];

    // Sentinel just above 6.25: update condition (d2 < bd) then accepts d2==6.25
    // (inclusive boundary, matching score>=0.5). Final scatter re-checks <=6.25
    // so a near-miss (6.25+1ulp) that survives can never be emitted.
    const float SENT = 6.250001f;

    float tx[4], ty[4], tcl[4], bd[4];
    int bp[4];
    #pragma unroll
    for (int j = 0; j < 4; j++) {
        int t = tblk * 16 + wave * 4 + j;
        const float* g = gt + ((size_t)b * NT + t) * 3;
        tcl[j] = g[0]; tx[j] = g[1]; ty[j] = g[2];
        bd[j] = SENT; bp[j] = 0x7fffffff;
    }

    for (int c = 0; c < NP; c += CP) {
        __syncthreads();
        const float4* src = pred + (size_t)b * NP + c;
        for (int i = threadIdx.x; i < CP; i += 256) sp[i] = src[i];
        __syncthreads();
        for (int i = 0; i < CP; i += 64) {
            float4 pr = sp[i + lane];
            int p = c + i + lane;
            #pragma unroll
            for (int j = 0; j < 4; j++) {
                float dx = pr.y - tx[j];
                float dy = pr.z - ty[j];
                float d2 = fmaf(dy, dy, dx * dx);
                // strict < keeps the earliest p per lane (ascending scan),
                // matching argmax first-index tie-break
                if ((pr.x == tcl[j]) && (d2 < bd[j])) { bd[j] = d2; bp[j] = p; }
            }
        }
    }

    #pragma unroll
    for (int j = 0; j < 4; j++) {
        float d = bd[j];
        int   p = bp[j];
        for (int off = 32; off; off >>= 1) {
            float od = __shfl_down(d, off, 64);
            int   op = __shfl_down(p, off, 64);
            if (od < d || (od == d && op < p)) { d = od; p = op; }
        }
        if (lane == 0 && d <= 6.25f) {
            unsigned gidx = (unsigned)(b * NP + p);
            unsigned old = atomicOr(&flags[gidx], 1u);
            if (old == 0u) {
                unsigned w = atomicAdd(counter, 1u);
                list[w] = gidx;
            }
        }
    }
}

// BCE-with-logits over all 65536 preds; wave reduce + one atomic per wave.
__global__ __launch_bounds__(256) void k_bce(const float4* __restrict__ pred,
                                             const unsigned* __restrict__ flags,
                                             float* __restrict__ bce_acc) {
    int i = blockIdx.x * 256 + threadIdx.x;   // grid covers exactly NB*NP
    float x = pred[i].w;
    float y = flags[i] ? 1.0f : 0.0f;
    float v = fmaxf(x, 0.0f) - x * y + log1pf(expf(-fabsf(x)));
    for (int off = 32; off; off >>= 1) v += __shfl_down(v, off, 64);
    if ((threadIdx.x & 63) == 0) atomicAdd(bce_acc, v);
}

// For each correct pred in the compacted list: min d^2 over ALL targets
// (reg uses unmasked max score), then sigmoid once; one wave per entry.
__global__ __launch_bounds__(256) void k_reg(const float4* __restrict__ pred,
                                             const float* __restrict__ gt,
                                             const unsigned* __restrict__ counter,
                                             const unsigned* __restrict__ list,
                                             float* __restrict__ score_acc) {
    int gwave = (int)((blockIdx.x * blockDim.x + threadIdx.x) >> 6);
    int lane  = threadIdx.x & 63;
    int nwaves = (int)((gridDim.x * blockDim.x) >> 6);
    unsigned n = *counter;
    for (unsigned e = gwave; e < n; e += nwaves) {
        unsigned gidx = list[e];
        int b = (int)(gidx >> 12);            // NP = 4096
        const float* g = gt + (size_t)b * NT * 3;
        float4 pr = pred[gidx];
        float cx = pr.y, cy = pr.z;
        float md = 1e30f;
        for (int t = lane; t < NT; t += 64) {
            float dx = cx - g[t * 3 + 1];
            float dy = cy - g[t * 3 + 2];
            md = fminf(md, fmaf(dy, dy, dx * dx));
        }
        for (int off = 32; off; off >>= 1)
            md = fminf(md, __shfl_down(md, off, 64));
        if (lane == 0) {
            float dd = sqrtf(md + 1e-12f);
            float s = 1.0f / (1.0f + expf(dd - 2.5f));
            atomicAdd(score_acc, s);
        }
    }
}

__global__ void k_final(const float* __restrict__ acc, float* __restrict__ out) {
    const float inv = 1.0f / (float)(NB * NP);
    out[0] = acc[0] * inv;          // obj_loss = sum(bce) / (B*P)
    out[1] = 1.0f - acc[1] * inv;   // reg_loss = 1 - sum(score over correct)/(B*P)
}

extern "C" void kernel_launch(void* const* d_in, const int* in_sizes, int n_in,
                              void* d_out, int out_size, void* d_ws, size_t ws_size,
                              hipStream_t stream) {
    const float4* pred = (const float4*)d_in[0];
    const float*  gt   = (const float*)d_in[1];

    unsigned* ws      = (unsigned*)d_ws;
    unsigned* flags   = ws;
    unsigned* counter = ws + NB * NP;
    float*    accs    = (float*)(ws + NB * NP + 1);
    unsigned* list    = ws + NB * NP + 3;

    const int nz = NB * NP + 3;   // flags + counter + 2 accums
    k_zero<<<(nz + 255) / 256, 256, 0, stream>>>(ws, nz);
    k_match<<<NB * 64, 256, 0, stream>>>(pred, gt, flags, counter, list);
    k_bce<<<NB * NP / 256, 256, 0, stream>>>(pred, flags, accs);
    k_reg<<<256, 256, 0, stream>>>(pred, gt, counter, list, accs + 1);
    k_final<<<1, 1, 0, stream>>>(accs, (float*)d_out);
}

// Round 2
// 143.945 us; speedup vs baseline: 1.0689x; 1.0689x over previous
//
#include <hip/hip_runtime.h>
#include <math.h>

// DotDetectionLoss on MI355X.
// pred: (16, 4096, 4) f32 = [cls, x, y, conf]  -> float4 loads
// gt:   (16, 1024, 3) f32 = [cls, x, y]
// out:  float[2] = {obj_loss, reg_loss}
//
// Math: scores = sigmoid(2.5 - d) monotone in d => argmax(score) == argmin(d^2),
// valid radius (score >= 0.5) <=> d^2 <= 6.25. correct[p] via atomicOr scatter of
// per-target argmin winners; reg term only for correct preds (per-image lists).

#define NB 16
#define NP 4096
#define NT 1024
#define TW 8          // targets per wave in k_match (VALU ops per LDS read = 8*TW)

// ws layout (4-byte words):
//   [0 .. NB*NP)              correct flags (unsigned)
//   [NB*NP .. NB*NP+16)       per-image list counters
//   [NB*NP+16]                bce sum (float)
//   [NB*NP+17]                score sum (float)
//   [NB*NP+18 .. +NB*NT)      per-image lists of correct local pred idx (b*NT+e)
#define WS_FLAGS   0
#define WS_CNT     (NB * NP)
#define WS_ACC     (NB * NP + 16)
#define WS_LIST    (NB * NP + 18)

// One block = 32 targets of one image; 4 waves x 8 targets each.
// Lanes stride over P; pred[b] staged through LDS in 1024-row chunks (16 KB).
// block=256: 512 blocks -> 2 blocks/CU, 8 waves/CU; ~60 VGPR so no occ cliff.
__global__ __launch_bounds__(256) void k_match(const float4* __restrict__ pred,
                                               const float* __restrict__ gt,
                                               unsigned* __restrict__ flags,
                                               unsigned* __restrict__ counters,
                                               unsigned* __restrict__ list) {
    const int CP = 1024;                 // pred chunk rows in LDS (16 KB)
    int b    = blockIdx.x >> 5;          // 32 blocks per image (1024 t / 32)
    int tblk = blockIdx.x & 31;
    int wave = threadIdx.x >> 6;
    int lane = threadIdx.x & 63;
    __shared__ float4 sp[CP];

    // Sentinel just above 6.25: (d2 < bd) accepts d2==6.25 (inclusive boundary,
    // matching score>=0.5). Final scatter re-checks <=6.25 so a 6.25+1ulp
    // near-miss can never be emitted.
    const float SENT = 6.250001f;

    float tx[TW], ty[TW], tcl[TW], bd[TW];
    int bp[TW];
    int t0 = tblk * 32 + wave * TW;
    #pragma unroll
    for (int j = 0; j < TW; j++) {
        const float* g = gt + ((size_t)b * NT + t0 + j) * 3;
        tcl[j] = g[0]; tx[j] = g[1]; ty[j] = g[2];
        bd[j] = SENT; bp[j] = 0x7fffffff;
    }

    for (int c = 0; c < NP; c += CP) {
        __syncthreads();
        const float4* src = pred + (size_t)b * NP + c;
        for (int i = threadIdx.x; i < CP; i += 256) sp[i] = src[i];
        __syncthreads();
        #pragma unroll 2
        for (int i = 0; i < CP; i += 64) {
            float4 pr = sp[i + lane];
            int p = c + i + lane;
            #pragma unroll
            for (int j = 0; j < TW; j++) {
                float dx = pr.y - tx[j];
                float dy = pr.z - ty[j];
                float d2 = fmaf(dy, dy, dx * dx);
                // strict < keeps the earliest p per lane (ascending scan),
                // matching argmax first-index tie-break
                if ((pr.x == tcl[j]) && (d2 < bd[j])) { bd[j] = d2; bp[j] = p; }
            }
        }
    }

    #pragma unroll
    for (int j = 0; j < TW; j++) {
        float d = bd[j];
        int   p = bp[j];
        for (int off = 32; off; off >>= 1) {
            float od = __shfl_down(d, off, 64);
            int   op = __shfl_down(p, off, 64);
            if (od < d || (od == d && op < p)) { d = od; p = op; }
        }
        if (lane == 0 && d <= 6.25f) {
            unsigned old = atomicOr(&flags[b * NP + p], 1u);
            if (old == 0u) {
                unsigned w = atomicAdd(&counters[b], 1u);
                list[b * NT + w] = (unsigned)p;
            }
        }
    }
}

// BCE-with-logits over all 65536 preds; wave reduce + one atomic per wave.
__global__ __launch_bounds__(256) void k_bce(const float4* __restrict__ pred,
                                             const unsigned* __restrict__ flags,
                                             float* __restrict__ bce_acc) {
    int i = blockIdx.x * 256 + threadIdx.x;   // grid covers exactly NB*NP
    float x = pred[i].w;
    float y = flags[i] ? 1.0f : 0.0f;
    float v = fmaxf(x, 0.0f) - x * y + log1pf(expf(-fabsf(x)));
    for (int off = 32; off; off >>= 1) v += __shfl_down(v, off, 64);
    if ((threadIdx.x & 63) == 0) atomicAdd(bce_acc, v);
}

// For each correct pred (per-image compacted list): min d^2 over ALL targets
// (reg uses unmasked max score), then sigmoid once. gt xy staged in LDS as
// float2 (2-way bank alias on b64 reads = free). 8 blocks per image; block
// accumulates in LDS, one global atomic per block.
__global__ __launch_bounds__(256) void k_reg(const float4* __restrict__ pred,
                                             const float* __restrict__ gt,
                                             const unsigned* __restrict__ counters,
                                             const unsigned* __restrict__ list,
                                             float* __restrict__ score_acc) {
    int b    = blockIdx.x >> 3;          // 128 blocks, 8 per image
    int sub  = blockIdx.x & 7;
    int wave = threadIdx.x >> 6;
    int lane = threadIdx.x & 63;
    __shared__ float2 sxy[NT];
    __shared__ float partial;
    if (threadIdx.x == 0) partial = 0.0f;
    const float* g = gt + (size_t)b * NT * 3;
    for (int t = threadIdx.x; t < NT; t += 256)
        sxy[t] = make_float2(g[t * 3 + 1], g[t * 3 + 2]);
    __syncthreads();

    unsigned n = counters[b];
    float local = 0.0f;
    for (unsigned e = (unsigned)(sub * 4 + wave); e < n; e += 32) {
        unsigned p = list[b * NT + e];
        float4 pr = pred[(size_t)b * NP + p];
        float cx = pr.y, cy = pr.z;
        float md = 1e30f;
        for (int t = lane; t < NT; t += 64) {
            float2 xy = sxy[t];
            float dx = cx - xy.x;
            float dy = cy - xy.y;
            md = fminf(md, fmaf(dy, dy, dx * dx));
        }
        for (int off = 32; off; off >>= 1)
            md = fminf(md, __shfl_down(md, off, 64));
        if (lane == 0) {
            float dd = sqrtf(md + 1e-12f);
            local += 1.0f / (1.0f + expf(dd - 2.5f));
        }
    }
    if (lane == 0 && local != 0.0f) atomicAdd(&partial, local);
    __syncthreads();
    if (threadIdx.x == 0 && partial != 0.0f) atomicAdd(score_acc, partial);
}

__global__ void k_final(const float* __restrict__ acc, float* __restrict__ out) {
    const float inv = 1.0f / (float)(NB * NP);
    out[0] = acc[0] * inv;          // obj_loss = sum(bce) / (B*P)
    out[1] = 1.0f - acc[1] * inv;   // reg_loss = 1 - sum(score over correct)/(B*P)
}

extern "C" void kernel_launch(void* const* d_in, const int* in_sizes, int n_in,
                              void* d_out, int out_size, void* d_ws, size_t ws_size,
                              hipStream_t stream) {
    const float4* pred = (const float4*)d_in[0];
    const float*  gt   = (const float*)d_in[1];

    unsigned* ws       = (unsigned*)d_ws;
    unsigned* flags    = ws + WS_FLAGS;
    unsigned* counters = ws + WS_CNT;
    float*    accs     = (float*)(ws + WS_ACC);
    unsigned* list     = ws + WS_LIST;

    // zero flags + counters + accumulators in one memset node (graph-capturable)
    hipMemsetAsync(ws, 0, (size_t)(NB * NP + 18) * 4, stream);
    k_match<<<NB * 32, 256, 0, stream>>>(pred, gt, flags, counters, list);
    k_bce<<<NB * NP / 256, 256, 0, stream>>>(pred, flags, accs);
    k_reg<<<NB * 8, 256, 0, stream>>>(pred, gt, counters, list, accs + 1);
    k_final<<<1, 1, 0, stream>>>(accs, (float*)d_out);
}